// Round 1
// baseline (95.987 us; speedup 1.0000x reference)
//
#include <hip/hip_runtime.h>

// LUT layer: out[b,o] = sum_d weights[d, idx[b,d], o]
// idx[b,d] = packed sign bits of x[b, anchors[d, 0..8]]
// B=2048, N_IN=1024, D=512, A=8, C=256, O=256

#define B_TOT   2048
#define N_IN    1024
#define N_DET   512
#define N_ANCH  8
#define N_OUT   256
#define BT      4      // batches per block

__global__ __launch_bounds__(256) void lut_fused_kernel(
    const float* __restrict__ x,
    const int*   __restrict__ anchors,
    const float* __restrict__ weights,
    float*       __restrict__ out)
{
    __shared__ float x_s[BT][N_IN];     // 16 KB
    __shared__ int   idx_s[BT][N_DET];  // 8 KB

    const int tid = threadIdx.x;
    const int b0  = blockIdx.x * BT;

    // ---- Phase A1: stage BT x-rows into LDS (coalesced float4) ----
    {
        const float4* xg = reinterpret_cast<const float4*>(x + (size_t)b0 * N_IN);
        float4*       xs = reinterpret_cast<float4*>(&x_s[0][0]);
        #pragma unroll
        for (int k = 0; k < BT; ++k) {
            xs[tid + k * 256] = xg[tid + k * 256];
        }
    }
    __syncthreads();

    // ---- Phase A2: compute LUT indices for all (bt, d) pairs ----
    // pairs = BT * 512 = 2048; 8 per thread; consecutive tid -> consecutive d
    #pragma unroll
    for (int k = 0; k < (BT * N_DET) / 256; ++k) {
        int p  = tid + k * 256;
        int d  = p & (N_DET - 1);
        int bt = p >> 9;                 // p / N_DET
        const int4* a4 = reinterpret_cast<const int4*>(anchors + d * N_ANCH);
        int4 a0 = a4[0];
        int4 a1 = a4[1];
        int idx = 0;
        idx |= (x_s[bt][a0.x] > 0.0f) ? 1   : 0;
        idx |= (x_s[bt][a0.y] > 0.0f) ? 2   : 0;
        idx |= (x_s[bt][a0.z] > 0.0f) ? 4   : 0;
        idx |= (x_s[bt][a0.w] > 0.0f) ? 8   : 0;
        idx |= (x_s[bt][a1.x] > 0.0f) ? 16  : 0;
        idx |= (x_s[bt][a1.y] > 0.0f) ? 32  : 0;
        idx |= (x_s[bt][a1.z] > 0.0f) ? 64  : 0;
        idx |= (x_s[bt][a1.w] > 0.0f) ? 128 : 0;
        idx_s[bt][d] = idx;
    }
    __syncthreads();

    // ---- Phase B: gather-accumulate weight rows ----
    // wave w owns batch bt=w; lane owns 4 output columns (float4)
    const int wave = tid >> 6;
    const int lane = tid & 63;
    const int bt   = wave;

    float4 acc = make_float4(0.0f, 0.0f, 0.0f, 0.0f);
    const float4* W4 = reinterpret_cast<const float4*>(weights);
    // weight row in float4 units: row length = N_OUT/4 = 64

    #pragma unroll 8
    for (int d = 0; d < N_DET; ++d) {
        int idx = idx_s[bt][d];                       // wave-uniform: LDS broadcast
        size_t row = (size_t)(d << 8) + (size_t)idx;  // d*256 + idx
        float4 w = W4[row * 64 + lane];               // coalesced 1 KB per wave
        acc.x += w.x;
        acc.y += w.y;
        acc.z += w.z;
        acc.w += w.w;
    }

    float4* out4 = reinterpret_cast<float4*>(out + (size_t)(b0 + bt) * N_OUT);
    out4[lane] = acc;
}

extern "C" void kernel_launch(void* const* d_in, const int* in_sizes, int n_in,
                              void* d_out, int out_size, void* d_ws, size_t ws_size,
                              hipStream_t stream) {
    const float* x       = (const float*)d_in[0];
    const int*   anchors = (const int*)  d_in[1];
    const float* weights = (const float*)d_in[2];
    float*       out     = (float*)d_out;

    dim3 grid(B_TOT / BT);   // 512 blocks
    dim3 block(256);
    lut_fused_kernel<<<grid, block, 0, stream>>>(x, anchors, weights, out);
}

// Round 2
// 62.176 us; speedup vs baseline: 1.5438x; 1.5438x over previous
//
#include <hip/hip_runtime.h>

// LUT layer: out[b,o] = sum_d weights[d, idx[b,d], o]
// idx[b,d] = packed sign bits of x[b, anchors[d, 0..8]]
// B=2048, N_IN=1024, D=512, A=8, C=256, O=256
//
// Strategy: detector-partition across XCDs.
//   K1: idx[b][d] (uint8, 1 MB in ws)
//   K2: 512 blocks = (64 batch-chunks x 8 det-groups); group = bid&7 -> XCD
//       affinity. Each XCD streams only its 16 MB of weight slabs; the 1 GB
//       gather reuse stays in per-XCD L2. Partials -> ws.
//   K3: reduce 8 partials -> out.

#define B_TOT   2048
#define N_IN    1024
#define N_DET   512
#define N_ANCH  8
#define N_OUT   256

#define DET_G   8            // detector groups (== XCDs)
#define DPG     (N_DET/DET_G)  // 64 detectors per group
#define BT2     32           // batches per block in gather kernel

#define IDX_BYTES   ((size_t)B_TOT * N_DET)                      // 1 MB
#define PART_BYTES  ((size_t)DET_G * B_TOT * N_OUT * sizeof(float)) // 16 MB

// ---------------- K1: compute LUT indices ----------------
__global__ __launch_bounds__(256) void lut_idx_kernel(
    const float* __restrict__ x,
    const int*   __restrict__ anchors,
    unsigned char* __restrict__ idx_out)
{
    __shared__ unsigned char bits[N_IN];
    const int b = blockIdx.x;
    const int t = threadIdx.x;

    const float4* xg = reinterpret_cast<const float4*>(x + (size_t)b * N_IN);
    float4 v = xg[t];
    bits[t * 4 + 0] = v.x > 0.0f;
    bits[t * 4 + 1] = v.y > 0.0f;
    bits[t * 4 + 2] = v.z > 0.0f;
    bits[t * 4 + 3] = v.w > 0.0f;
    __syncthreads();

    #pragma unroll
    for (int k = 0; k < N_DET / 256; ++k) {
        int d = t + k * 256;
        const int4* a4 = reinterpret_cast<const int4*>(anchors + d * N_ANCH);
        int4 a0 = a4[0];
        int4 a1 = a4[1];
        unsigned idx = 0;
        idx |= (unsigned)bits[a0.x];
        idx |= (unsigned)bits[a0.y] << 1;
        idx |= (unsigned)bits[a0.z] << 2;
        idx |= (unsigned)bits[a0.w] << 3;
        idx |= (unsigned)bits[a1.x] << 4;
        idx |= (unsigned)bits[a1.y] << 5;
        idx |= (unsigned)bits[a1.z] << 6;
        idx |= (unsigned)bits[a1.w] << 7;
        idx_out[(size_t)b * N_DET + d] = (unsigned char)idx;
    }
}

// ---------------- K2: gather-accumulate per detector group ----------------
__global__ __launch_bounds__(256) void lut_gather_kernel(
    const unsigned char* __restrict__ idx,
    const float* __restrict__ weights,
    float* __restrict__ partial)
{
    const int bid = blockIdx.x;
    const int g   = bid & (DET_G - 1);   // det group -> XCD (round-robin)
    const int bc  = bid >> 3;            // batch chunk
    const int b0  = bc * BT2;
    const int d0  = g * DPG;

    __shared__ unsigned char idx_s[DPG][BT2];  // transposed [d][b], 2 KB

    const int t = threadIdx.x;
    // stage idx block: thread t loads 8 bytes for batch r=t>>3, cols cc=t&7
    {
        int r  = t >> 3;
        int cc = t & 7;
        uint2 v = *reinterpret_cast<const uint2*>(
            idx + (size_t)(b0 + r) * N_DET + d0 + cc * 8);
        unsigned char* bs = (unsigned char*)&v;
        #pragma unroll
        for (int i = 0; i < 8; ++i) idx_s[cc * 8 + i][r] = bs[i];
    }
    __syncthreads();

    const int wave = t >> 6;
    const int lane = t & 63;

    float4 acc[8];
    #pragma unroll
    for (int j = 0; j < 8; ++j) acc[j] = make_float4(0.f, 0.f, 0.f, 0.f);

    const float4* W4 = reinterpret_cast<const float4*>(weights)
                     + (size_t)d0 * 256 * 64;   // group base (row=256 ch x 64 f4)

    for (int d = 0; d < DPG; ++d) {
        uint2 cv = *reinterpret_cast<const uint2*>(&idx_s[d][wave * 8]);
        unsigned lo = cv.x, hi = cv.y;
        const float4* Wd = W4 + (size_t)d * 256 * 64 + lane;
        #pragma unroll
        for (int j = 0; j < 4; ++j) {
            unsigned c = (lo >> (8 * j)) & 0xFF;
            float4 w = Wd[(size_t)c * 64];
            acc[j].x += w.x; acc[j].y += w.y; acc[j].z += w.z; acc[j].w += w.w;
        }
        #pragma unroll
        for (int j = 0; j < 4; ++j) {
            unsigned c = (hi >> (8 * j)) & 0xFF;
            float4 w = Wd[(size_t)c * 64];
            acc[4+j].x += w.x; acc[4+j].y += w.y; acc[4+j].z += w.z; acc[4+j].w += w.w;
        }
    }

    float4* P4 = reinterpret_cast<float4*>(partial);
    #pragma unroll
    for (int j = 0; j < 8; ++j) {
        size_t b = (size_t)b0 + wave * 8 + j;
        P4[((size_t)g * B_TOT + b) * 64 + lane] = acc[j];
    }
}

// ---------------- K3: reduce partials ----------------
__global__ __launch_bounds__(256) void lut_reduce_kernel(
    const float* __restrict__ partial,
    float* __restrict__ out)
{
    const size_t i = (size_t)blockIdx.x * 256 + threadIdx.x; // over 2048*64 f4
    const float4* P4 = reinterpret_cast<const float4*>(partial);
    float4 s = make_float4(0.f, 0.f, 0.f, 0.f);
    #pragma unroll
    for (int g = 0; g < DET_G; ++g) {
        float4 v = P4[(size_t)g * (B_TOT * 64) + i];
        s.x += v.x; s.y += v.y; s.z += v.z; s.w += v.w;
    }
    reinterpret_cast<float4*>(out)[i] = s;
}

// ---------------- fallback: round-1 monolithic kernel ----------------
#define BT 4
__global__ __launch_bounds__(256) void lut_fused_kernel(
    const float* __restrict__ x,
    const int*   __restrict__ anchors,
    const float* __restrict__ weights,
    float*       __restrict__ out)
{
    __shared__ float x_s[BT][N_IN];
    __shared__ int   idx_s[BT][N_DET];
    const int tid = threadIdx.x;
    const int b0  = blockIdx.x * BT;
    {
        const float4* xg = reinterpret_cast<const float4*>(x + (size_t)b0 * N_IN);
        float4*       xs = reinterpret_cast<float4*>(&x_s[0][0]);
        #pragma unroll
        for (int k = 0; k < BT; ++k) xs[tid + k * 256] = xg[tid + k * 256];
    }
    __syncthreads();
    #pragma unroll
    for (int k = 0; k < (BT * N_DET) / 256; ++k) {
        int p  = tid + k * 256;
        int d  = p & (N_DET - 1);
        int bt = p >> 9;
        const int4* a4 = reinterpret_cast<const int4*>(anchors + d * N_ANCH);
        int4 a0 = a4[0];
        int4 a1 = a4[1];
        int idx = 0;
        idx |= (x_s[bt][a0.x] > 0.0f) ? 1   : 0;
        idx |= (x_s[bt][a0.y] > 0.0f) ? 2   : 0;
        idx |= (x_s[bt][a0.z] > 0.0f) ? 4   : 0;
        idx |= (x_s[bt][a0.w] > 0.0f) ? 8   : 0;
        idx |= (x_s[bt][a1.x] > 0.0f) ? 16  : 0;
        idx |= (x_s[bt][a1.y] > 0.0f) ? 32  : 0;
        idx |= (x_s[bt][a1.z] > 0.0f) ? 64  : 0;
        idx |= (x_s[bt][a1.w] > 0.0f) ? 128 : 0;
        idx_s[bt][d] = idx;
    }
    __syncthreads();
    const int wave = tid >> 6;
    const int lane = tid & 63;
    float4 acc = make_float4(0.0f, 0.0f, 0.0f, 0.0f);
    const float4* W4 = reinterpret_cast<const float4*>(weights);
    #pragma unroll 8
    for (int d = 0; d < N_DET; ++d) {
        int idx = idx_s[wave][d];
        size_t row = (size_t)(d << 8) + (size_t)idx;
        float4 w = W4[row * 64 + lane];
        acc.x += w.x; acc.y += w.y; acc.z += w.z; acc.w += w.w;
    }
    float4* out4 = reinterpret_cast<float4*>(out + (size_t)(b0 + wave) * N_OUT);
    out4[lane] = acc;
}

extern "C" void kernel_launch(void* const* d_in, const int* in_sizes, int n_in,
                              void* d_out, int out_size, void* d_ws, size_t ws_size,
                              hipStream_t stream) {
    const float* x       = (const float*)d_in[0];
    const int*   anchors = (const int*)  d_in[1];
    const float* weights = (const float*)d_in[2];
    float*       out     = (float*)d_out;

    if (ws_size >= IDX_BYTES + PART_BYTES) {
        unsigned char* idx_ws  = (unsigned char*)d_ws;
        float*         part_ws = (float*)((char*)d_ws + IDX_BYTES);

        lut_idx_kernel<<<dim3(B_TOT), dim3(256), 0, stream>>>(x, anchors, idx_ws);
        lut_gather_kernel<<<dim3((B_TOT / BT2) * DET_G), dim3(256), 0, stream>>>(
            idx_ws, weights, part_ws);
        lut_reduce_kernel<<<dim3(B_TOT * N_OUT / 4 / 256), dim3(256), 0, stream>>>(
            part_ws, out);
    } else {
        lut_fused_kernel<<<dim3(B_TOT / BT), dim3(256), 0, stream>>>(
            x, anchors, weights, out);
    }
}